// Round 1
// baseline (1629.778 us; speedup 1.0000x reference)
//
#include <hip/hip_runtime.h>

#define N_NODES   50000
#define N_EDGES   1600000
#define N_GRAPHS  512
#define IN_SIZE   44
#define HIDDEN    256
#define CONV_NUMS 3

// ---------------------------------------------------------------------------
// Workspace layout (all offsets 256B-aligned), total ~105.9 MiB:
//   h       : N*H fp32   (51.2 MB)   current node features
//   t       : N*H fp32   (51.2 MB)   h + mean-agg (GEMM input)
//   col     : E  int     (6.4 MB)    CSR col indices (src per dst-row)
//   row_ptr : N+1 int
//   cursor  : N   int
//   counts  : N   int
//   Gsum    : 3*G*H fp32 (1.57 MB)   per-graph feature sums per layer
//   gcnt    : G   int
// ---------------------------------------------------------------------------

__global__ void k_count_deg(const int* __restrict__ dst, int* __restrict__ counts) {
    for (int e = blockIdx.x * blockDim.x + threadIdx.x; e < N_EDGES;
         e += gridDim.x * blockDim.x)
        atomicAdd(&counts[dst[e]], 1);
}

__global__ void k_count_graph(const int* __restrict__ gid, int* __restrict__ gcnt) {
    for (int v = blockIdx.x * blockDim.x + threadIdx.x; v < N_NODES;
         v += gridDim.x * blockDim.x)
        atomicAdd(&gcnt[gid[v]], 1);
}

// single-block exclusive scan of counts -> row_ptr (and cursor copy)
__global__ void k_scan(const int* __restrict__ counts, int* __restrict__ row_ptr,
                       int* __restrict__ cursor) {
    const int T = 1024;
    const int CH = (N_NODES + T - 1) / T;  // 49
    __shared__ int lds[T];
    int t = threadIdx.x;
    int base = t * CH;
    int s = 0;
    for (int i = 0; i < CH; i++) {
        int idx = base + i;
        if (idx < N_NODES) s += counts[idx];
    }
    lds[t] = s;
    __syncthreads();
    // Hillis-Steele inclusive scan
    for (int off = 1; off < T; off <<= 1) {
        int v = lds[t];
        int add = (t >= off) ? lds[t - off] : 0;
        __syncthreads();
        lds[t] = v + add;
        __syncthreads();
    }
    int run = lds[t] - s;  // exclusive prefix
    for (int i = 0; i < CH; i++) {
        int idx = base + i;
        if (idx < N_NODES) {
            row_ptr[idx] = run;
            cursor[idx] = run;
            run += counts[idx];
        }
    }
    if (t == T - 1) row_ptr[N_NODES] = lds[T - 1];
}

__global__ void k_fill(const int* __restrict__ src, const int* __restrict__ dst,
                       int* __restrict__ cursor, int* __restrict__ col) {
    for (int e = blockIdx.x * blockDim.x + threadIdx.x; e < N_EDGES;
         e += gridDim.x * blockDim.x) {
        int d = dst[e];
        int pos = atomicAdd(&cursor[d], 1);
        col[pos] = src[e];
    }
}

// h = X @ W_proj + b_proj   (one node per block, thread = out column)
__global__ __launch_bounds__(HIDDEN) void k_proj(const float* __restrict__ X,
                                                 const float* __restrict__ Wp,
                                                 const float* __restrict__ bp,
                                                 float* __restrict__ h) {
    __shared__ float x[IN_SIZE];
    int v = blockIdx.x;
    int c = threadIdx.x;
    if (c < IN_SIZE) x[c] = X[v * IN_SIZE + c];
    __syncthreads();
    float acc = bp[c];
#pragma unroll
    for (int k = 0; k < IN_SIZE; k++) acc += x[k] * Wp[k * HIDDEN + c];
    h[v * HIDDEN + c] = acc;
}

// t[v] = h[v] + inv_deg[v] * sum_{u in N_in(v)} h[u]   (one wave per node)
__global__ __launch_bounds__(256) void k_agg(const float* __restrict__ h,
                                             const int* __restrict__ row_ptr,
                                             const int* __restrict__ col,
                                             float* __restrict__ t) {
    int wid = threadIdx.x >> 6;
    int lane = threadIdx.x & 63;
    int v = blockIdx.x * 4 + wid;
    if (v >= N_NODES) return;
    int s = row_ptr[v], e = row_ptr[v + 1];
    const float4* hv = (const float4*)h;
    float ax = 0.f, ay = 0.f, az = 0.f, aw = 0.f;
    int i = s;
    for (; i + 4 <= e; i += 4) {
        int u0 = col[i], u1 = col[i + 1], u2 = col[i + 2], u3 = col[i + 3];
        float4 a = hv[u0 * 64 + lane];
        float4 b = hv[u1 * 64 + lane];
        float4 c = hv[u2 * 64 + lane];
        float4 d = hv[u3 * 64 + lane];
        ax += a.x + b.x + c.x + d.x;
        ay += a.y + b.y + c.y + d.y;
        az += a.z + b.z + c.z + d.z;
        aw += a.w + b.w + c.w + d.w;
    }
    for (; i < e; i++) {
        int u = col[i];
        float4 a = hv[u * 64 + lane];
        ax += a.x; ay += a.y; az += a.z; aw += a.w;
    }
    float inv = (e > s) ? 1.0f / (float)(e - s) : 0.0f;
    float4 hvv = hv[v * 64 + lane];
    float4 o;
    o.x = hvv.x + inv * ax;
    o.y = hvv.y + inv * ay;
    o.z = hvv.z + inv * az;
    o.w = hvv.w + inv * aw;
    ((float4*)t)[v * 64 + lane] = o;
}

// hout = tin @ W (256x256) + b ; 32 rows per block, thread tile = 8 rows x 4 cols
__global__ __launch_bounds__(256) void k_linear(const float* __restrict__ tin,
                                                const float* __restrict__ W,
                                                const float* __restrict__ b,
                                                float* __restrict__ hout) {
    __shared__ float tl[32 * 256];
    int row0 = blockIdx.x * 32;
    int tid = threadIdx.x;
    // stage 32x256 input tile
    for (int i = tid; i < 32 * 64; i += 256) {
        int r = i >> 6, c4 = i & 63;
        int row = row0 + r;
        float4 val = make_float4(0.f, 0.f, 0.f, 0.f);
        if (row < N_NODES) val = ((const float4*)tin)[row * 64 + c4];
        ((float4*)tl)[r * 64 + c4] = val;
    }
    __syncthreads();

    int cg = tid & 63;   // columns 4*cg .. 4*cg+3
    int rg = tid >> 6;   // rows rg*8 .. rg*8+7 of the tile
    float4 acc[8];
#pragma unroll
    for (int r = 0; r < 8; r++) acc[r] = make_float4(0.f, 0.f, 0.f, 0.f);

    const float4* W4 = (const float4*)W;
    const float4* tl4 = (const float4*)tl;
    for (int k0 = 0; k0 < 256; k0 += 4) {
        float4 w0 = W4[(k0 + 0) * 64 + cg];
        float4 w1 = W4[(k0 + 1) * 64 + cg];
        float4 w2 = W4[(k0 + 2) * 64 + cg];
        float4 w3 = W4[(k0 + 3) * 64 + cg];
#pragma unroll
        for (int r = 0; r < 8; r++) {
            float4 tv = tl4[(rg * 8 + r) * 64 + (k0 >> 2)];  // broadcast read
            acc[r].x += tv.x * w0.x + tv.y * w1.x + tv.z * w2.x + tv.w * w3.x;
            acc[r].y += tv.x * w0.y + tv.y * w1.y + tv.z * w2.y + tv.w * w3.y;
            acc[r].z += tv.x * w0.z + tv.y * w1.z + tv.z * w2.z + tv.w * w3.z;
            acc[r].w += tv.x * w0.w + tv.y * w1.w + tv.z * w2.w + tv.w * w3.w;
        }
    }
    float4 bb = ((const float4*)b)[cg];
#pragma unroll
    for (int r = 0; r < 8; r++) {
        int row = row0 + rg * 8 + r;
        if (row < N_NODES) {
            float4 o;
            o.x = acc[r].x + bb.x;
            o.y = acc[r].y + bb.y;
            o.z = acc[r].z + bb.z;
            o.w = acc[r].w + bb.w;
            ((float4*)hout)[row * 64 + cg] = o;
        }
    }
}

// per-graph sums of h into GsumL (graph_ids sorted -> run-length + few atomics)
__global__ __launch_bounds__(256) void k_readout(const float* __restrict__ h,
                                                 const int* __restrict__ gid,
                                                 float* __restrict__ GsumL) {
    const int CHUNK = 128;
    int base = blockIdx.x * CHUNK;
    int c = threadIdx.x;
    __shared__ int gl[CHUNK];
    for (int i = threadIdx.x; i < CHUNK; i += 256) {
        int v = base + i;
        gl[i] = (v < N_NODES) ? gid[v] : -1;
    }
    __syncthreads();
    float acc = 0.f;
    int cur = gl[0];
    for (int i = 0; i < CHUNK; i++) {
        int v = base + i;
        if (v >= N_NODES) break;
        int g = gl[i];
        if (g != cur) {
            atomicAdd(&GsumL[cur * HIDDEN + c], acc);
            acc = 0.f;
            cur = g;
        }
        acc += h[v * HIDDEN + c];
    }
    if (cur >= 0) atomicAdd(&GsumL[cur * HIDDEN + c], acc);
}

// out[g] = (concat of Gsum[l][g]/cnt) @ W_out + b_out   (one graph per block)
__global__ __launch_bounds__(256) void k_out(const float* __restrict__ Gsum,
                                             const int* __restrict__ gcnt,
                                             const float* __restrict__ Wout,
                                             const float* __restrict__ bout,
                                             float* __restrict__ out) {
    int g = blockIdx.x;
    int c = threadIdx.x;
    __shared__ float gm[HIDDEN * CONV_NUMS];
    float invc = 1.0f / fmaxf((float)gcnt[g], 1.0f);
    for (int i = c; i < HIDDEN * CONV_NUMS; i += 256) {
        int l = i >> 8;    // / 256
        int k = i & 255;   // % 256
        gm[i] = Gsum[(size_t)l * N_GRAPHS * HIDDEN + g * HIDDEN + k] * invc;
    }
    __syncthreads();
    float acc = bout[c];
    const float4* gm4 = (const float4*)gm;
    for (int k0 = 0; k0 < HIDDEN * CONV_NUMS; k0 += 4) {
        float4 gv = gm4[k0 >> 2];
        acc += gv.x * Wout[(k0 + 0) * HIDDEN + c];
        acc += gv.y * Wout[(k0 + 1) * HIDDEN + c];
        acc += gv.z * Wout[(k0 + 2) * HIDDEN + c];
        acc += gv.w * Wout[(k0 + 3) * HIDDEN + c];
    }
    out[g * HIDDEN + c] = acc;
}

extern "C" void kernel_launch(void* const* d_in, const int* in_sizes, int n_in,
                              void* d_out, int out_size, void* d_ws, size_t ws_size,
                              hipStream_t stream) {
    const float* X     = (const float*)d_in[0];
    const int*   src   = (const int*)d_in[1];
    const int*   dst   = (const int*)d_in[2];
    const int*   gid   = (const int*)d_in[3];
    const float* Wp    = (const float*)d_in[4];
    const float* bp    = (const float*)d_in[5];
    const float* Wl    = (const float*)d_in[6];
    const float* bl    = (const float*)d_in[7];
    const float* Wout  = (const float*)d_in[8];
    const float* bout  = (const float*)d_in[9];
    float* out = (float*)d_out;

    char* ws = (char*)d_ws;
    size_t off = 0;
    auto alloc = [&](size_t bytes) {
        char* p = ws + off;
        off += (bytes + 255) & ~size_t(255);
        return p;
    };
    float* h       = (float*)alloc(sizeof(float) * N_NODES * HIDDEN);
    float* t       = (float*)alloc(sizeof(float) * N_NODES * HIDDEN);
    int*   col     = (int*)alloc(sizeof(int) * N_EDGES);
    int*   row_ptr = (int*)alloc(sizeof(int) * (N_NODES + 1));
    int*   cursor  = (int*)alloc(sizeof(int) * N_NODES);
    int*   counts  = (int*)alloc(sizeof(int) * N_NODES);
    float* Gsum    = (float*)alloc(sizeof(float) * CONV_NUMS * N_GRAPHS * HIDDEN);
    int*   gcnt    = (int*)alloc(sizeof(int) * N_GRAPHS);

    hipMemsetAsync(counts, 0, sizeof(int) * N_NODES, stream);
    hipMemsetAsync(Gsum, 0, sizeof(float) * CONV_NUMS * N_GRAPHS * HIDDEN, stream);
    hipMemsetAsync(gcnt, 0, sizeof(int) * N_GRAPHS, stream);

    k_count_deg<<<2048, 256, 0, stream>>>(dst, counts);
    k_count_graph<<<256, 256, 0, stream>>>(gid, gcnt);
    k_scan<<<1, 1024, 0, stream>>>(counts, row_ptr, cursor);
    k_fill<<<2048, 256, 0, stream>>>(src, dst, cursor, col);

    k_proj<<<N_NODES, HIDDEN, 0, stream>>>(X, Wp, bp, h);

    for (int l = 0; l < CONV_NUMS; l++) {
        k_agg<<<(N_NODES + 3) / 4, 256, 0, stream>>>(h, row_ptr, col, t);
        k_linear<<<(N_NODES + 31) / 32, 256, 0, stream>>>(t, Wl, bl, h);
        k_readout<<<(N_NODES + 127) / 128, 256, 0, stream>>>(
            h, gid, Gsum + (size_t)l * N_GRAPHS * HIDDEN);
    }

    k_out<<<N_GRAPHS, HIDDEN, 0, stream>>>(Gsum, gcnt, Wout, bout, out);
}

// Round 2
// 1022.657 us; speedup vs baseline: 1.5937x; 1.5937x over previous
//
#include <hip/hip_runtime.h>

#define N_NODES   50000
#define N_EDGES   1600000
#define N_GRAPHS  512
#define IN_SIZE   44
#define HIDDEN    256
#define CONV_NUMS 3

typedef __attribute__((ext_vector_type(8))) short short8v;   // 8 bf16 = 16 B (MFMA A/B frag)
typedef __attribute__((ext_vector_type(4))) float f32x4;     // MFMA C/D frag

__device__ __forceinline__ float bf2f(unsigned short u) {
    return __uint_as_float(((unsigned int)u) << 16);
}
__device__ __forceinline__ unsigned short f2bf(float f) {
    unsigned int u = __float_as_uint(f);
    unsigned int r = (u + 0x7fffu + ((u >> 16) & 1u)) >> 16;  // RNE
    return (unsigned short)r;
}

// ---------------- graph build ----------------
__global__ void k_count_deg(const int* __restrict__ dst, int* __restrict__ counts) {
    for (int e = blockIdx.x * blockDim.x + threadIdx.x; e < N_EDGES;
         e += gridDim.x * blockDim.x)
        atomicAdd(&counts[dst[e]], 1);
}

__global__ void k_count_graph(const int* __restrict__ gid, int* __restrict__ gcnt) {
    for (int v = blockIdx.x * blockDim.x + threadIdx.x; v < N_NODES;
         v += gridDim.x * blockDim.x)
        atomicAdd(&gcnt[gid[v]], 1);
}

__global__ void k_scan(const int* __restrict__ counts, int* __restrict__ row_ptr,
                       int* __restrict__ cursor) {
    const int T = 1024;
    const int CH = (N_NODES + T - 1) / T;
    __shared__ int lds[T];
    int t = threadIdx.x;
    int base = t * CH;
    int s = 0;
    for (int i = 0; i < CH; i++) {
        int idx = base + i;
        if (idx < N_NODES) s += counts[idx];
    }
    lds[t] = s;
    __syncthreads();
    for (int off = 1; off < T; off <<= 1) {
        int v = lds[t];
        int add = (t >= off) ? lds[t - off] : 0;
        __syncthreads();
        lds[t] = v + add;
        __syncthreads();
    }
    int run = lds[t] - s;
    for (int i = 0; i < CH; i++) {
        int idx = base + i;
        if (idx < N_NODES) {
            row_ptr[idx] = run;
            cursor[idx] = run;
            run += counts[idx];
        }
    }
    if (t == T - 1) row_ptr[N_NODES] = lds[T - 1];
}

__global__ void k_fill(const int* __restrict__ src, const int* __restrict__ dst,
                       int* __restrict__ cursor, int* __restrict__ col) {
    for (int e = blockIdx.x * blockDim.x + threadIdx.x; e < N_EDGES;
         e += gridDim.x * blockDim.x) {
        int d = dst[e];
        int pos = atomicAdd(&cursor[d], 1);
        col[pos] = src[e];
    }
}

// ---------------- W_lin repack for MFMA B-fragments ----------------
// Wp[(kg*256 + n)*8 + j] = bf16(W[kg*8 + j][n]),  kg in [0,32), n,j per above.
// Lane L of a wave then loads its B-frag (16 B) at kg = ks*4 + (L>>4), n = n0 + (L&15):
// consecutive lanes of a quad -> 16 consecutive short8v -> 256 B contiguous.
__global__ __launch_bounds__(256) void k_pack_w(const float* __restrict__ W,
                                                unsigned short* __restrict__ Wp) {
    int i = blockIdx.x * 256 + threadIdx.x;   // 8192 total
    int kg = i >> 8, n = i & 255;
    short8v v;
#pragma unroll
    for (int j = 0; j < 8; j++) v[j] = (short)f2bf(W[(kg * 8 + j) * HIDDEN + n]);
    *(short8v*)(Wp + (size_t)(kg * 256 + n) * 8) = v;
}

// ---------------- initial projection: h = X @ W_proj + b (fp32 math, bf16 out) ----
__global__ __launch_bounds__(HIDDEN) void k_proj(const float* __restrict__ X,
                                                 const float* __restrict__ Wp,
                                                 const float* __restrict__ bp,
                                                 unsigned short* __restrict__ h) {
    __shared__ float x[IN_SIZE];
    int v = blockIdx.x;
    int c = threadIdx.x;
    if (c < IN_SIZE) x[c] = X[v * IN_SIZE + c];
    __syncthreads();
    float acc = bp[c];
#pragma unroll
    for (int k = 0; k < IN_SIZE; k++) acc += x[k] * Wp[k * HIDDEN + c];
    h[v * HIDDEN + c] = f2bf(acc);
}

// ---------------- t[v] = h[v] + inv_deg * sum h[u]  (bf16 gather, one wave/node) ----
__global__ __launch_bounds__(256) void k_agg(const unsigned short* __restrict__ h,
                                             const int* __restrict__ row_ptr,
                                             const int* __restrict__ col,
                                             unsigned short* __restrict__ t) {
    int wid = threadIdx.x >> 6;
    int lane = threadIdx.x & 63;
    int v = blockIdx.x * 4 + wid;
    if (v >= N_NODES) return;
    int s = row_ptr[v], e = row_ptr[v + 1];
    const ushort4* hv = (const ushort4*)h;   // 4 bf16 per lane (8 B)
    float a0 = 0.f, a1 = 0.f, a2 = 0.f, a3 = 0.f;
    int i = s;
    for (; i + 4 <= e; i += 4) {
        int u0 = col[i], u1 = col[i + 1], u2 = col[i + 2], u3 = col[i + 3];
        ushort4 p = hv[u0 * 64 + lane];
        ushort4 q = hv[u1 * 64 + lane];
        ushort4 r = hv[u2 * 64 + lane];
        ushort4 w = hv[u3 * 64 + lane];
        a0 += bf2f(p.x) + bf2f(q.x) + bf2f(r.x) + bf2f(w.x);
        a1 += bf2f(p.y) + bf2f(q.y) + bf2f(r.y) + bf2f(w.y);
        a2 += bf2f(p.z) + bf2f(q.z) + bf2f(r.z) + bf2f(w.z);
        a3 += bf2f(p.w) + bf2f(q.w) + bf2f(r.w) + bf2f(w.w);
    }
    for (; i < e; i++) {
        ushort4 p = hv[col[i] * 64 + lane];
        a0 += bf2f(p.x); a1 += bf2f(p.y); a2 += bf2f(p.z); a3 += bf2f(p.w);
    }
    float inv = (e > s) ? 1.0f / (float)(e - s) : 0.0f;
    ushort4 hs = hv[v * 64 + lane];
    ushort4 o;
    o.x = f2bf(bf2f(hs.x) + inv * a0);
    o.y = f2bf(bf2f(hs.y) + inv * a1);
    o.z = f2bf(bf2f(hs.z) + inv * a2);
    o.w = f2bf(bf2f(hs.w) + inv * a3);
    ((ushort4*)t)[v * 64 + lane] = o;
}

// ---------------- h' = t @ W_lin + b  via bf16 MFMA 16x16x32 ----------------
// Block: 256 thr = 4 waves; tile 64 rows x 256 cols; wave w -> cols [w*64, w*64+64).
// A frag: lane holds A[m = l16][k = quad*8 + j] -> 16 B contiguous row-major load.
// B frag from Wp (see k_pack_w). C/D: col = l16, row = quad*4 + r.
__global__ __launch_bounds__(256) void k_linear_mfma(const unsigned short* __restrict__ A,
                                                     const unsigned short* __restrict__ Wp,
                                                     const float* __restrict__ bias,
                                                     unsigned short* __restrict__ Out) {
    int w = threadIdx.x >> 6;
    int lane = threadIdx.x & 63;
    int quad = lane >> 4;
    int l16 = lane & 15;
    int m0 = blockIdx.x * 64;
    int n0 = w * 64;

    f32x4 acc[4][4];
#pragma unroll
    for (int mt = 0; mt < 4; mt++)
#pragma unroll
        for (int nt = 0; nt < 4; nt++) acc[mt][nt] = (f32x4){0.f, 0.f, 0.f, 0.f};

#pragma unroll
    for (int ks = 0; ks < 8; ks++) {
        short8v afr[4], bfr[4];
#pragma unroll
        for (int mt = 0; mt < 4; mt++) {
            int row = m0 + mt * 16 + l16;
            row = (row < N_NODES) ? row : (N_NODES - 1);
            afr[mt] = *(const short8v*)(A + (size_t)row * HIDDEN + ks * 32 + quad * 8);
        }
#pragma unroll
        for (int nt = 0; nt < 4; nt++) {
            int n = n0 + nt * 16 + l16;
            int kg = ks * 4 + quad;
            bfr[nt] = *(const short8v*)(Wp + (size_t)(kg * 256 + n) * 8);
        }
#pragma unroll
        for (int mt = 0; mt < 4; mt++)
#pragma unroll
            for (int nt = 0; nt < 4; nt++)
                acc[mt][nt] = __builtin_amdgcn_mfma_f32_16x16x32_bf16(
                    afr[mt], bfr[nt], acc[mt][nt], 0, 0, 0);
    }

#pragma unroll
    for (int nt = 0; nt < 4; nt++) {
        int colg = n0 + nt * 16 + l16;
        float bb = bias[colg];
#pragma unroll
        for (int mt = 0; mt < 4; mt++) {
#pragma unroll
            for (int r = 0; r < 4; r++) {
                int row = m0 + mt * 16 + quad * 4 + r;
                if (row < N_NODES)
                    Out[(size_t)row * HIDDEN + colg] = f2bf(acc[mt][nt][r] + bb);
            }
        }
    }
}

// ---------------- per-graph sums (sorted graph_ids -> run-length + atomics) ----
__global__ __launch_bounds__(256) void k_readout(const unsigned short* __restrict__ h,
                                                 const int* __restrict__ gid,
                                                 float* __restrict__ GsumL) {
    const int CHUNK = 64;
    int base = blockIdx.x * CHUNK;
    int c = threadIdx.x;
    __shared__ int gl[CHUNK];
    for (int i = threadIdx.x; i < CHUNK; i += 256) {
        int v = base + i;
        gl[i] = (v < N_NODES) ? gid[v] : -1;
    }
    __syncthreads();
    float acc = 0.f;
    int cur = gl[0];
    for (int i = 0; i < CHUNK; i++) {
        int v = base + i;
        if (v >= N_NODES) break;
        int g = gl[i];
        if (g != cur) {
            atomicAdd(&GsumL[cur * HIDDEN + c], acc);
            acc = 0.f;
            cur = g;
        }
        acc += bf2f(h[(size_t)v * HIDDEN + c]);
    }
    if (cur >= 0) atomicAdd(&GsumL[cur * HIDDEN + c], acc);
}

// ---------------- out[g] = (concat gmean) @ W_out + b_out ----------------
__global__ __launch_bounds__(256) void k_out(const float* __restrict__ Gsum,
                                             const int* __restrict__ gcnt,
                                             const float* __restrict__ Wout,
                                             const float* __restrict__ bout,
                                             float* __restrict__ out) {
    int g = blockIdx.x;
    int c = threadIdx.x;
    __shared__ float gm[HIDDEN * CONV_NUMS];
    float invc = 1.0f / fmaxf((float)gcnt[g], 1.0f);
    for (int i = c; i < HIDDEN * CONV_NUMS; i += 256) {
        int l = i >> 8;
        int k = i & 255;
        gm[i] = Gsum[(size_t)l * N_GRAPHS * HIDDEN + g * HIDDEN + k] * invc;
    }
    __syncthreads();
    float acc = bout[c];
    const float4* gm4 = (const float4*)gm;
    for (int k0 = 0; k0 < HIDDEN * CONV_NUMS; k0 += 4) {
        float4 gv = gm4[k0 >> 2];
        acc += gv.x * Wout[(k0 + 0) * HIDDEN + c];
        acc += gv.y * Wout[(k0 + 1) * HIDDEN + c];
        acc += gv.z * Wout[(k0 + 2) * HIDDEN + c];
        acc += gv.w * Wout[(k0 + 3) * HIDDEN + c];
    }
    out[g * HIDDEN + c] = acc;
}

extern "C" void kernel_launch(void* const* d_in, const int* in_sizes, int n_in,
                              void* d_out, int out_size, void* d_ws, size_t ws_size,
                              hipStream_t stream) {
    const float* X    = (const float*)d_in[0];
    const int*   src  = (const int*)d_in[1];
    const int*   dst  = (const int*)d_in[2];
    const int*   gid  = (const int*)d_in[3];
    const float* Wp   = (const float*)d_in[4];
    const float* bp   = (const float*)d_in[5];
    const float* Wl   = (const float*)d_in[6];
    const float* bl   = (const float*)d_in[7];
    const float* Wout = (const float*)d_in[8];
    const float* bout = (const float*)d_in[9];
    float* out = (float*)d_out;

    char* ws = (char*)d_ws;
    size_t off = 0;
    auto alloc = [&](size_t bytes) {
        char* p = ws + off;
        off += (bytes + 255) & ~size_t(255);
        return p;
    };
    unsigned short* h     = (unsigned short*)alloc(sizeof(short) * N_NODES * HIDDEN);
    unsigned short* t     = (unsigned short*)alloc(sizeof(short) * N_NODES * HIDDEN);
    unsigned short* Wpack = (unsigned short*)alloc(sizeof(short) * HIDDEN * HIDDEN);
    int*   col     = (int*)alloc(sizeof(int) * N_EDGES);
    int*   row_ptr = (int*)alloc(sizeof(int) * (N_NODES + 1));
    int*   cursor  = (int*)alloc(sizeof(int) * N_NODES);
    int*   counts  = (int*)alloc(sizeof(int) * N_NODES);
    float* Gsum    = (float*)alloc(sizeof(float) * CONV_NUMS * N_GRAPHS * HIDDEN);
    int*   gcnt    = (int*)alloc(sizeof(int) * N_GRAPHS);

    hipMemsetAsync(counts, 0, sizeof(int) * N_NODES, stream);
    hipMemsetAsync(Gsum, 0, sizeof(float) * CONV_NUMS * N_GRAPHS * HIDDEN, stream);
    hipMemsetAsync(gcnt, 0, sizeof(int) * N_GRAPHS, stream);

    k_count_deg<<<2048, 256, 0, stream>>>(dst, counts);
    k_count_graph<<<256, 256, 0, stream>>>(gid, gcnt);
    k_scan<<<1, 1024, 0, stream>>>(counts, row_ptr, cursor);
    k_fill<<<2048, 256, 0, stream>>>(src, dst, cursor, col);
    k_pack_w<<<32, 256, 0, stream>>>(Wl, Wpack);

    k_proj<<<N_NODES, HIDDEN, 0, stream>>>(X, Wp, bp, h);

    for (int l = 0; l < CONV_NUMS; l++) {
        k_agg<<<(N_NODES + 3) / 4, 256, 0, stream>>>(h, row_ptr, col, t);
        k_linear_mfma<<<(N_NODES + 63) / 64, 256, 0, stream>>>(t, Wpack, bl, h);
        k_readout<<<(N_NODES + 63) / 64, 256, 0, stream>>>(
            h, gid, Gsum + (size_t)l * N_GRAPHS * HIDDEN);
    }

    k_out<<<N_GRAPHS, HIDDEN, 0, stream>>>(Gsum, gcnt, Wout, bout, out);
}

// Round 3
// 878.422 us; speedup vs baseline: 1.8553x; 1.1642x over previous
//
#include <hip/hip_runtime.h>

#define N_NODES   50000
#define N_EDGES   1600000
#define N_GRAPHS  512
#define IN_SIZE   44
#define HIDDEN    256
#define CONV_NUMS 3

typedef __attribute__((ext_vector_type(8))) short short8v;   // 8 bf16 = 16 B (MFMA A/B frag)
typedef __attribute__((ext_vector_type(4))) float f32x4;     // MFMA C/D frag

__device__ __forceinline__ float bf2f(unsigned short u) {
    return __uint_as_float(((unsigned int)u) << 16);
}
__device__ __forceinline__ unsigned short f2bf(float f) {
    unsigned int u = __float_as_uint(f);
    unsigned int r = (u + 0x7fffu + ((u >> 16) & 1u)) >> 16;  // RNE
    return (unsigned short)r;
}

// ---------------- graph build ----------------
// merged degree + graph-size histograms
__global__ void k_count(const int* __restrict__ dst, const int* __restrict__ gid,
                        int* __restrict__ counts, int* __restrict__ gcnt) {
    int t = blockIdx.x * blockDim.x + threadIdx.x;
    int stride = gridDim.x * blockDim.x;
    for (int e = t; e < N_EDGES; e += stride) atomicAdd(&counts[dst[e]], 1);
    for (int v = t; v < N_NODES; v += stride) atomicAdd(&gcnt[gid[v]], 1);
}

// scan stage A: per-1024-chunk sums (coalesced)
__global__ __launch_bounds__(256) void k_scan_a(const int* __restrict__ counts,
                                                int* __restrict__ bsum) {
    __shared__ int sh[256];
    int b = blockIdx.x;
    int s = 0;
    for (int i = threadIdx.x; i < 1024; i += 256) {
        int g = b * 1024 + i;
        if (g < N_NODES) s += counts[g];
    }
    sh[threadIdx.x] = s;
    __syncthreads();
    for (int off = 128; off > 0; off >>= 1) {
        if (threadIdx.x < off) sh[threadIdx.x] += sh[threadIdx.x + off];
        __syncthreads();
    }
    if (threadIdx.x == 0) bsum[b] = sh[0];
}

// scan stage B: exclusive scan of 49 chunk sums, write total
__global__ void k_scan_b(const int* __restrict__ bsum, int* __restrict__ boff,
                         int* __restrict__ row_ptr) {
    const int NB = (N_NODES + 1023) / 1024;  // 49
    __shared__ int s[NB];
    int t = threadIdx.x;
    if (t < NB) s[t] = bsum[t];
    __syncthreads();
    if (t == 0) {
        int run = 0;
        for (int i = 0; i < NB; i++) { int v = s[i]; s[i] = run; run += v; }
        row_ptr[N_NODES] = run;
    }
    __syncthreads();
    if (t < NB) boff[t] = s[t];
}

// scan stage C: per-chunk local scan + offset, write row_ptr + cursor
__global__ __launch_bounds__(256) void k_scan_c(const int* __restrict__ counts,
                                                const int* __restrict__ boff,
                                                int* __restrict__ row_ptr,
                                                int* __restrict__ cursor) {
    __shared__ int vals[1024];
    __shared__ int tsum[256];
    int b = blockIdx.x;
    int t = threadIdx.x;
    for (int i = t; i < 1024; i += 256) {
        int g = b * 1024 + i;
        vals[i] = (g < N_NODES) ? counts[g] : 0;
    }
    __syncthreads();
    int local = vals[4 * t] + vals[4 * t + 1] + vals[4 * t + 2] + vals[4 * t + 3];
    tsum[t] = local;
    __syncthreads();
    for (int off = 1; off < 256; off <<= 1) {
        int add = (t >= off) ? tsum[t - off] : 0;
        __syncthreads();
        tsum[t] += add;
        __syncthreads();
    }
    int run = boff[b] + tsum[t] - local;  // exclusive prefix
    for (int j = 0; j < 4; j++) {
        int g = b * 1024 + 4 * t + j;
        if (g < N_NODES) {
            row_ptr[g] = run;
            cursor[g] = run;
            run += vals[4 * t + j];
        }
    }
}

// batched fill: 4 edges/thread, independent atomics then stores
__global__ __launch_bounds__(256) void k_fill(const int* __restrict__ src,
                                              const int* __restrict__ dst,
                                              int* __restrict__ cursor,
                                              int* __restrict__ col) {
    int t = blockIdx.x * blockDim.x + threadIdx.x;
    int base = t * 4;
    if (base >= N_EDGES) return;
    int4 d4 = *(const int4*)(dst + base);
    int4 s4 = *(const int4*)(src + base);
    int p0 = atomicAdd(&cursor[d4.x], 1);
    int p1 = atomicAdd(&cursor[d4.y], 1);
    int p2 = atomicAdd(&cursor[d4.z], 1);
    int p3 = atomicAdd(&cursor[d4.w], 1);
    col[p0] = s4.x;
    col[p1] = s4.y;
    col[p2] = s4.z;
    col[p3] = s4.w;
}

// ---------------- W_lin repack for MFMA B-fragments ----------------
__global__ __launch_bounds__(256) void k_pack_w(const float* __restrict__ W,
                                                unsigned short* __restrict__ Wp) {
    int i = blockIdx.x * 256 + threadIdx.x;   // 8192 total
    int kg = i >> 8, n = i & 255;
    short8v v;
#pragma unroll
    for (int j = 0; j < 8; j++) v[j] = (short)f2bf(W[(kg * 8 + j) * HIDDEN + n]);
    *(short8v*)(Wp + (size_t)(kg * 256 + n) * 8) = v;
}

// ---------------- initial projection, block-batched, W in LDS ----------------
__global__ __launch_bounds__(256) void k_proj(const float* __restrict__ X,
                                              const float* __restrict__ Wp,
                                              const float* __restrict__ bp,
                                              unsigned short* __restrict__ h) {
    __shared__ float WL[IN_SIZE * HIDDEN];   // 45056 B
    __shared__ float bL[HIDDEN];
    __shared__ float xb[8 * IN_SIZE];        // 1408 B
    int tid = threadIdx.x;
    for (int i = tid; i < IN_SIZE * HIDDEN; i += 256) WL[i] = Wp[i];
    if (tid < HIDDEN) bL[tid] = bp[tid];
    __syncthreads();
    int c = tid;
    int r0blk = blockIdx.x * 256;            // 196 blocks x 256 rows
    for (int batch = 0; batch < 32; batch++) {
        int r0 = r0blk + batch * 8;
        for (int i = tid; i < 8 * IN_SIZE; i += 256) {
            int g = r0 * IN_SIZE + i;
            xb[i] = (g < N_NODES * IN_SIZE) ? X[g] : 0.f;
        }
        __syncthreads();
        float acc[8];
#pragma unroll
        for (int j = 0; j < 8; j++) acc[j] = bL[c];
        for (int k = 0; k < IN_SIZE; k++) {
            float wk = WL[k * HIDDEN + c];
#pragma unroll
            for (int j = 0; j < 8; j++) acc[j] += xb[j * IN_SIZE + k] * wk;
        }
#pragma unroll
        for (int j = 0; j < 8; j++) {
            int row = r0 + j;
            if (row < N_NODES) h[(size_t)row * HIDDEN + c] = f2bf(acc[j]);
        }
        __syncthreads();
    }
}

// ---------------- fused layer: gather -> LDS -> MFMA -> store + readout -------
// Block: 256 thr = 4 waves; tile = 64 rows x 256 cols. LDS tile stride 272
// shorts (544 B): A-frag ds_read_b128 bank pattern is 2-way max (free).
#define TLS 272
__global__ __launch_bounds__(256) void k_layer(const unsigned short* __restrict__ h,
                                               const int* __restrict__ row_ptr,
                                               const int* __restrict__ col,
                                               const unsigned short* __restrict__ Wpack,
                                               const float* __restrict__ bias,
                                               const int* __restrict__ gid,
                                               unsigned short* __restrict__ hout,
                                               float* __restrict__ GsumL) {
    __shared__ unsigned short tl[64 * TLS];
    __shared__ int gl[64];
    int tid = threadIdx.x;
    int w = tid >> 6, lane = tid & 63, quad = lane >> 4, l16 = lane & 15;
    int m0 = blockIdx.x * 64;

    // ---- phase 1: gather+mean into LDS tile (wave w -> rows w*16..w*16+15) ----
    const ushort4* hv = (const ushort4*)h;
    for (int rr = 0; rr < 16; rr++) {
        int r = w * 16 + rr;
        int v = m0 + r;
        float a0 = 0.f, a1 = 0.f, a2 = 0.f, a3 = 0.f;
        if (v < N_NODES) {
            int s = row_ptr[v], e = row_ptr[v + 1];
            int i = s;
            for (; i + 4 <= e; i += 4) {
                int u0 = col[i], u1 = col[i + 1], u2 = col[i + 2], u3 = col[i + 3];
                ushort4 p = hv[(size_t)u0 * 64 + lane];
                ushort4 q = hv[(size_t)u1 * 64 + lane];
                ushort4 x = hv[(size_t)u2 * 64 + lane];
                ushort4 y = hv[(size_t)u3 * 64 + lane];
                a0 += bf2f(p.x) + bf2f(q.x) + bf2f(x.x) + bf2f(y.x);
                a1 += bf2f(p.y) + bf2f(q.y) + bf2f(x.y) + bf2f(y.y);
                a2 += bf2f(p.z) + bf2f(q.z) + bf2f(x.z) + bf2f(y.z);
                a3 += bf2f(p.w) + bf2f(q.w) + bf2f(x.w) + bf2f(y.w);
            }
            for (; i < e; i++) {
                ushort4 p = hv[(size_t)col[i] * 64 + lane];
                a0 += bf2f(p.x); a1 += bf2f(p.y); a2 += bf2f(p.z); a3 += bf2f(p.w);
            }
            float inv = (e > s) ? 1.0f / (float)(e - s) : 0.0f;
            ushort4 hs = hv[(size_t)v * 64 + lane];
            a0 = bf2f(hs.x) + inv * a0;
            a1 = bf2f(hs.y) + inv * a1;
            a2 = bf2f(hs.z) + inv * a2;
            a3 = bf2f(hs.w) + inv * a3;
        }
        ushort4 o;
        o.x = f2bf(a0); o.y = f2bf(a1); o.z = f2bf(a2); o.w = f2bf(a3);
        *(ushort4*)(tl + r * TLS + lane * 4) = o;
    }
    if (tid < 64) gl[tid] = (m0 + tid < N_NODES) ? gid[m0 + tid] : -1;
    __syncthreads();

    // ---- phase 2: MFMA 64x64 per wave (cols n0..n0+63) ----
    int n0 = w * 64;
    f32x4 acc[4][4];
#pragma unroll
    for (int mt = 0; mt < 4; mt++)
#pragma unroll
        for (int nt = 0; nt < 4; nt++) acc[mt][nt] = (f32x4){0.f, 0.f, 0.f, 0.f};

#pragma unroll
    for (int ks = 0; ks < 8; ks++) {
        short8v afr[4], bfr[4];
#pragma unroll
        for (int mt = 0; mt < 4; mt++)
            afr[mt] = *(const short8v*)(tl + (mt * 16 + l16) * TLS + ks * 32 + quad * 8);
#pragma unroll
        for (int nt = 0; nt < 4; nt++) {
            int n = n0 + nt * 16 + l16;
            int kg = ks * 4 + quad;
            bfr[nt] = *(const short8v*)(Wpack + (size_t)(kg * 256 + n) * 8);
        }
#pragma unroll
        for (int mt = 0; mt < 4; mt++)
#pragma unroll
            for (int nt = 0; nt < 4; nt++)
                acc[mt][nt] = __builtin_amdgcn_mfma_f32_16x16x32_bf16(
                    afr[mt], bfr[nt], acc[mt][nt], 0, 0, 0);
    }
    __syncthreads();  // all A-frag reads done before tile overwrite

    // ---- phase 3: epilogue -> bf16 back into LDS tile ----
#pragma unroll
    for (int nt = 0; nt < 4; nt++) {
        int colg = n0 + nt * 16 + l16;
        float bb = bias[colg];
#pragma unroll
        for (int mt = 0; mt < 4; mt++)
#pragma unroll
            for (int r = 0; r < 4; r++) {
                int row = mt * 16 + quad * 4 + r;
                tl[row * TLS + colg] = f2bf(acc[mt][nt][r] + bb);
            }
    }
    __syncthreads();

    // ---- phase 4a: coalesced global store (64 rows x 512 B) ----
    for (int i = tid; i < 64 * 64; i += 256) {
        int r = i >> 6, c4 = i & 63;
        int v = m0 + r;
        if (v < N_NODES)
            ((ushort4*)hout)[(size_t)v * 64 + c4] = *(ushort4*)(tl + r * TLS + c4 * 4);
    }
    // ---- phase 4b: fused readout (thread = column, run-merge sorted gids) ----
    {
        int c = tid;
        float acc2 = 0.f;
        int cur = gl[0];
        for (int r = 0; r < 64; r++) {
            int g = gl[r];
            if (g < 0) break;
            if (g != cur) {
                atomicAdd(&GsumL[cur * HIDDEN + c], acc2);
                acc2 = 0.f;
                cur = g;
            }
            acc2 += bf2f(tl[r * TLS + c]);
        }
        if (cur >= 0) atomicAdd(&GsumL[cur * HIDDEN + c], acc2);
    }
}

// ---------------- out[g] = (concat gmean) @ W_out + b_out ----------------
__global__ __launch_bounds__(256) void k_out(const float* __restrict__ Gsum,
                                             const int* __restrict__ gcnt,
                                             const float* __restrict__ Wout,
                                             const float* __restrict__ bout,
                                             float* __restrict__ out) {
    int g = blockIdx.x;
    int c = threadIdx.x;
    __shared__ float gm[HIDDEN * CONV_NUMS];
    float invc = 1.0f / fmaxf((float)gcnt[g], 1.0f);
    for (int i = c; i < HIDDEN * CONV_NUMS; i += 256) {
        int l = i >> 8;
        int k = i & 255;
        gm[i] = Gsum[(size_t)l * N_GRAPHS * HIDDEN + g * HIDDEN + k] * invc;
    }
    __syncthreads();
    float acc = bout[c];
    const float4* gm4 = (const float4*)gm;
    for (int k0 = 0; k0 < HIDDEN * CONV_NUMS; k0 += 4) {
        float4 gv = gm4[k0 >> 2];
        acc += gv.x * Wout[(k0 + 0) * HIDDEN + c];
        acc += gv.y * Wout[(k0 + 1) * HIDDEN + c];
        acc += gv.z * Wout[(k0 + 2) * HIDDEN + c];
        acc += gv.w * Wout[(k0 + 3) * HIDDEN + c];
    }
    out[g * HIDDEN + c] = acc;
}

extern "C" void kernel_launch(void* const* d_in, const int* in_sizes, int n_in,
                              void* d_out, int out_size, void* d_ws, size_t ws_size,
                              hipStream_t stream) {
    const float* X    = (const float*)d_in[0];
    const int*   src  = (const int*)d_in[1];
    const int*   dst  = (const int*)d_in[2];
    const int*   gid  = (const int*)d_in[3];
    const float* Wp   = (const float*)d_in[4];
    const float* bp   = (const float*)d_in[5];
    const float* Wl   = (const float*)d_in[6];
    const float* bl   = (const float*)d_in[7];
    const float* Wout = (const float*)d_in[8];
    const float* bout = (const float*)d_in[9];
    float* out = (float*)d_out;

    char* ws = (char*)d_ws;
    size_t off = 0;
    auto alloc = [&](size_t bytes) {
        char* p = ws + off;
        off += (bytes + 255) & ~size_t(255);
        return p;
    };
    unsigned short* h     = (unsigned short*)alloc(sizeof(short) * N_NODES * HIDDEN);
    unsigned short* t     = (unsigned short*)alloc(sizeof(short) * N_NODES * HIDDEN);
    unsigned short* Wpack = (unsigned short*)alloc(sizeof(short) * HIDDEN * HIDDEN);
    int*   col     = (int*)alloc(sizeof(int) * N_EDGES);
    int*   row_ptr = (int*)alloc(sizeof(int) * (N_NODES + 1));
    int*   cursor  = (int*)alloc(sizeof(int) * N_NODES);
    int*   counts  = (int*)alloc(sizeof(int) * N_NODES);
    float* Gsum    = (float*)alloc(sizeof(float) * CONV_NUMS * N_GRAPHS * HIDDEN);
    int*   gcnt    = (int*)alloc(sizeof(int) * N_GRAPHS);
    int*   bsum    = (int*)alloc(sizeof(int) * 64);
    int*   boff    = (int*)alloc(sizeof(int) * 64);

    const int NB = (N_NODES + 1023) / 1024;  // 49

    hipMemsetAsync(counts, 0, sizeof(int) * N_NODES, stream);
    hipMemsetAsync(Gsum, 0, sizeof(float) * CONV_NUMS * N_GRAPHS * HIDDEN, stream);
    hipMemsetAsync(gcnt, 0, sizeof(int) * N_GRAPHS, stream);

    k_count<<<2048, 256, 0, stream>>>(dst, gid, counts, gcnt);
    k_scan_a<<<NB, 256, 0, stream>>>(counts, bsum);
    k_scan_b<<<1, 64, 0, stream>>>(bsum, boff, row_ptr);
    k_scan_c<<<NB, 256, 0, stream>>>(counts, boff, row_ptr, cursor);
    k_fill<<<(N_EDGES / 4 + 255) / 256, 256, 0, stream>>>(src, dst, cursor, col);
    k_pack_w<<<32, 256, 0, stream>>>(Wl, Wpack);

    k_proj<<<(N_NODES + 255) / 256, 256, 0, stream>>>(X, Wp, bp, h);

    unsigned short* cur = h;
    unsigned short* nxt = t;
    for (int l = 0; l < CONV_NUMS; l++) {
        k_layer<<<(N_NODES + 63) / 64, 256, 0, stream>>>(
            cur, row_ptr, col, Wpack, bl, gid, nxt,
            Gsum + (size_t)l * N_GRAPHS * HIDDEN);
        unsigned short* tmp = cur; cur = nxt; nxt = tmp;
    }

    k_out<<<N_GRAPHS, 256, 0, stream>>>(Gsum, gcnt, Wout, bout, out);
}

// Round 4
// 623.127 us; speedup vs baseline: 2.6155x; 1.4097x over previous
//
#include <hip/hip_runtime.h>

#define N_NODES   50000
#define N_EDGES   1600000
#define N_GRAPHS  512
#define IN_SIZE   44
#define HIDDEN    256
#define CONV_NUMS 3
#define NBK       ((N_NODES + 255) / 256)   // 196 dst-buckets of 256 nodes

typedef __attribute__((ext_vector_type(8))) short short8v;   // 8 bf16 = 16 B
typedef __attribute__((ext_vector_type(4))) float f32x4;     // MFMA C/D frag

__device__ __forceinline__ float bf2f(unsigned short u) {
    return __uint_as_float(((unsigned int)u) << 16);
}
__device__ __forceinline__ unsigned short f2bf(float f) {
    unsigned int u = __float_as_uint(f);
    unsigned int r = (u + 0x7fffu + ((u >> 16) & 1u)) >> 16;  // RNE
    return (unsigned short)r;
}

// ============================ graph build ===================================
// Pass A: bucket histogram (dst>>8) + per-graph node counts, LDS-aggregated.
__global__ __launch_bounds__(256) void k_passA(const int* __restrict__ dst,
                                               const int* __restrict__ gid,
                                               int* __restrict__ bucket_cnt,
                                               int* __restrict__ gcnt) {
    __shared__ int hb[NBK];
    __shared__ int hg[N_GRAPHS];
    int tid = threadIdx.x;
    for (int i = tid; i < NBK; i += 256) hb[i] = 0;
    for (int i = tid; i < N_GRAPHS; i += 256) hg[i] = 0;
    __syncthreads();
    int t = blockIdx.x * 256 + tid;
    int stride = gridDim.x * 256;
    for (int e = t; e < N_EDGES; e += stride) atomicAdd(&hb[dst[e] >> 8], 1);
    for (int v = t; v < N_NODES; v += stride) atomicAdd(&hg[gid[v]], 1);
    __syncthreads();
    for (int i = tid; i < NBK; i += 256) if (hb[i]) atomicAdd(&bucket_cnt[i], hb[i]);
    for (int i = tid; i < N_GRAPHS; i += 256) if (hg[i]) atomicAdd(&gcnt[i], hg[i]);
}

// scan of 196 bucket counts -> bucket_base / bucket_cursor
__global__ void k_bscan(const int* __restrict__ bucket_cnt, int* __restrict__ bucket_base,
                        int* __restrict__ bucket_cursor, int* __restrict__ row_ptr) {
    __shared__ int s[256];
    int t = threadIdx.x;
    int v = (t < NBK) ? bucket_cnt[t] : 0;
    s[t] = v;
    __syncthreads();
    for (int off = 1; off < 256; off <<= 1) {
        int a = (t >= off) ? s[t - off] : 0;
        __syncthreads();
        s[t] += a;
        __syncthreads();
    }
    if (t < NBK) {
        int base = s[t] - v;
        bucket_base[t] = base;
        bucket_cursor[t] = base;
    }
    if (t == 0) {
        bucket_base[NBK] = N_EDGES;
        row_ptr[N_NODES] = N_EDGES;
    }
}

// Pass B: LDS-sort 4096-edge chunks by bucket, write (src,dst) pairs in runs.
#define BCH 4096
__global__ __launch_bounds__(256) void k_passB(const int* __restrict__ src,
                                               const int* __restrict__ dst,
                                               int* __restrict__ bucket_cursor,
                                               int2* __restrict__ pairs) {
    __shared__ int hist[NBK];
    __shared__ int excl[NBK];
    __shared__ int cur[NBK];
    __shared__ int gbase[NBK];
    __shared__ int2 lp[BCH];
    __shared__ int sc[256];
    int tid = threadIdx.x;
    int e0 = blockIdx.x * BCH;
    int cnt = min(BCH, N_EDGES - e0);
    for (int i = tid; i < NBK; i += 256) hist[i] = 0;
    __syncthreads();
    for (int i = tid; i < cnt; i += 256) atomicAdd(&hist[dst[e0 + i] >> 8], 1);
    __syncthreads();
    int hv = (tid < NBK) ? hist[tid] : 0;
    sc[tid] = hv;
    __syncthreads();
    for (int off = 1; off < 256; off <<= 1) {
        int a = (tid >= off) ? sc[tid - off] : 0;
        __syncthreads();
        sc[tid] += a;
        __syncthreads();
    }
    if (tid < NBK) {
        excl[tid] = sc[tid] - hv;
        cur[tid]  = sc[tid] - hv;
    }
    __syncthreads();
    for (int i = tid; i < cnt; i += 256) {
        int d = dst[e0 + i];
        int b = d >> 8;
        int pos = atomicAdd(&cur[b], 1);
        lp[pos] = make_int2(src[e0 + i], d);
    }
    __syncthreads();
    if (tid < NBK && hist[tid] > 0)
        gbase[tid] = atomicAdd(&bucket_cursor[tid], hist[tid]);
    __syncthreads();
    for (int i = tid; i < cnt; i += 256) {
        int2 p = lp[i];
        int b = p.y >> 8;
        pairs[gbase[b] + (i - excl[b])] = p;
    }
}

// Pass C: one block per bucket -> row_ptr + col (all writes single-CU local)
__global__ __launch_bounds__(256) void k_passC(const int2* __restrict__ pairs,
                                               const int* __restrict__ bucket_base,
                                               int* __restrict__ row_ptr,
                                               int* __restrict__ col) {
    __shared__ int hist[256];
    __shared__ int cur[256];
    __shared__ int sc[256];
    int b = blockIdx.x;
    int tid = threadIdx.x;
    int v0 = b << 8;
    int e0 = bucket_base[b], e1 = bucket_base[b + 1];
    hist[tid] = 0;
    __syncthreads();
    for (int i = e0 + tid; i < e1; i += 256) atomicAdd(&hist[pairs[i].y - v0], 1);
    __syncthreads();
    int hv = hist[tid];
    sc[tid] = hv;
    __syncthreads();
    for (int off = 1; off < 256; off <<= 1) {
        int a = (tid >= off) ? sc[tid - off] : 0;
        __syncthreads();
        sc[tid] += a;
        __syncthreads();
    }
    int base = e0 + sc[tid] - hv;
    int v = v0 + tid;
    if (v < N_NODES) row_ptr[v] = base;
    cur[tid] = base;
    __syncthreads();
    for (int i = e0 + tid; i < e1; i += 256) {
        int2 p = pairs[i];
        int pos = atomicAdd(&cur[p.y - v0], 1);
        col[pos] = p.x;
    }
}

// ===================== W_lin repack for MFMA B-fragments ====================
__global__ __launch_bounds__(256) void k_pack_w(const float* __restrict__ W,
                                                unsigned short* __restrict__ Wp) {
    int i = blockIdx.x * 256 + threadIdx.x;   // 8192 total
    int kg = i >> 8, n = i & 255;
    short8v v;
#pragma unroll
    for (int j = 0; j < 8; j++) v[j] = (short)f2bf(W[(kg * 8 + j) * HIDDEN + n]);
    *(short8v*)(Wp + (size_t)(kg * 256 + n) * 8) = v;
}

// ============ initial projection, block-batched, W_proj in LDS ==============
__global__ __launch_bounds__(256) void k_proj(const float* __restrict__ X,
                                              const float* __restrict__ Wp,
                                              const float* __restrict__ bp,
                                              unsigned short* __restrict__ h) {
    __shared__ float WL[IN_SIZE * HIDDEN];
    __shared__ float bL[HIDDEN];
    __shared__ float xb[8 * IN_SIZE];
    int tid = threadIdx.x;
    for (int i = tid; i < IN_SIZE * HIDDEN; i += 256) WL[i] = Wp[i];
    if (tid < HIDDEN) bL[tid] = bp[tid];
    __syncthreads();
    int c = tid;
    int r0blk = blockIdx.x * 256;
    for (int batch = 0; batch < 32; batch++) {
        int r0 = r0blk + batch * 8;
        for (int i = tid; i < 8 * IN_SIZE; i += 256) {
            int g = r0 * IN_SIZE + i;
            xb[i] = (g < N_NODES * IN_SIZE) ? X[g] : 0.f;
        }
        __syncthreads();
        float acc[8];
#pragma unroll
        for (int j = 0; j < 8; j++) acc[j] = bL[c];
        for (int k = 0; k < IN_SIZE; k++) {
            float wk = WL[k * HIDDEN + c];
#pragma unroll
            for (int j = 0; j < 8; j++) acc[j] += xb[j * IN_SIZE + k] * wk;
        }
#pragma unroll
        for (int j = 0; j < 8; j++) {
            int row = r0 + j;
            if (row < N_NODES) h[(size_t)row * HIDDEN + c] = f2bf(acc[j]);
        }
        __syncthreads();
    }
}

// ====== fused layer: gather -> LDS -> MFMA -> coalesced store + readout =====
// 512 thr = 8 waves; tile 64 rows x 256 cols; LDS stride 264 shorts (33.8 KB)
// -> 4 blocks/CU = 32 waves/CU. Wave w gathers rows [w*8, w*8+8), MFMA cols
// [w*32, w*32+32). __launch_bounds__(512,8) caps VGPR at 64 for 8 waves/EU.
#define TLS 264
__global__ __launch_bounds__(512, 8) void k_layer(const unsigned short* __restrict__ h,
                                                  const int* __restrict__ row_ptr,
                                                  const int* __restrict__ col,
                                                  const unsigned short* __restrict__ Wpack,
                                                  const float* __restrict__ bias,
                                                  const int* __restrict__ gid,
                                                  unsigned short* __restrict__ hout,
                                                  float* __restrict__ GsumL) {
    __shared__ unsigned short tl[64 * TLS];   // 33792 B
    __shared__ int gl[64];
    int tid = threadIdx.x;
    int w = tid >> 6, lane = tid & 63, quad = lane >> 4, l16 = lane & 15;
    int m0 = blockIdx.x * 64;

    // ---- phase 1: gather + mean into LDS tile ----
    const ushort4* hv = (const ushort4*)h;
    for (int rr = 0; rr < 8; rr++) {
        int r = w * 8 + rr;
        int v = m0 + r;
        float a0 = 0.f, a1 = 0.f, a2 = 0.f, a3 = 0.f;
        if (v < N_NODES) {
            int s = row_ptr[v], e = row_ptr[v + 1];
            int i = s;
            for (; i + 4 <= e; i += 4) {
                int u0 = col[i], u1 = col[i + 1], u2 = col[i + 2], u3 = col[i + 3];
                ushort4 p = hv[(size_t)u0 * 64 + lane];
                ushort4 q = hv[(size_t)u1 * 64 + lane];
                ushort4 x = hv[(size_t)u2 * 64 + lane];
                ushort4 y = hv[(size_t)u3 * 64 + lane];
                a0 += bf2f(p.x) + bf2f(q.x) + bf2f(x.x) + bf2f(y.x);
                a1 += bf2f(p.y) + bf2f(q.y) + bf2f(x.y) + bf2f(y.y);
                a2 += bf2f(p.z) + bf2f(q.z) + bf2f(x.z) + bf2f(y.z);
                a3 += bf2f(p.w) + bf2f(q.w) + bf2f(x.w) + bf2f(y.w);
            }
            for (; i < e; i++) {
                ushort4 p = hv[(size_t)col[i] * 64 + lane];
                a0 += bf2f(p.x); a1 += bf2f(p.y); a2 += bf2f(p.z); a3 += bf2f(p.w);
            }
            float inv = (e > s) ? 1.0f / (float)(e - s) : 0.0f;
            ushort4 hs = hv[(size_t)v * 64 + lane];
            a0 = bf2f(hs.x) + inv * a0;
            a1 = bf2f(hs.y) + inv * a1;
            a2 = bf2f(hs.z) + inv * a2;
            a3 = bf2f(hs.w) + inv * a3;
        }
        ushort4 o;
        o.x = f2bf(a0); o.y = f2bf(a1); o.z = f2bf(a2); o.w = f2bf(a3);
        *(ushort4*)(tl + r * TLS + lane * 4) = o;
    }
    if (tid < 64) gl[tid] = (m0 + tid < N_NODES) ? gid[m0 + tid] : -1;
    __syncthreads();

    // ---- phase 2: MFMA, wave w -> cols [w*32, w*32+32) ----
    int n0 = w * 32;
    f32x4 acc[4][2];
#pragma unroll
    for (int mt = 0; mt < 4; mt++) {
        acc[mt][0] = (f32x4){0.f, 0.f, 0.f, 0.f};
        acc[mt][1] = (f32x4){0.f, 0.f, 0.f, 0.f};
    }
#pragma unroll
    for (int ks = 0; ks < 8; ks++) {
        int kg = ks * 4 + quad;
        short8v bfr0 = *(const short8v*)(Wpack + (size_t)(kg * 256 + n0 + l16) * 8);
        short8v bfr1 = *(const short8v*)(Wpack + (size_t)(kg * 256 + n0 + 16 + l16) * 8);
#pragma unroll
        for (int mt = 0; mt < 4; mt++) {
            short8v afr = *(const short8v*)(tl + (mt * 16 + l16) * TLS + ks * 32 + quad * 8);
            acc[mt][0] = __builtin_amdgcn_mfma_f32_16x16x32_bf16(afr, bfr0, acc[mt][0], 0, 0, 0);
            acc[mt][1] = __builtin_amdgcn_mfma_f32_16x16x32_bf16(afr, bfr1, acc[mt][1], 0, 0, 0);
        }
    }
    __syncthreads();  // A-frag reads complete before tile overwrite

    // ---- phase 3: epilogue -> bf16 back into LDS ----
#pragma unroll
    for (int nt = 0; nt < 2; nt++) {
        int colg = n0 + nt * 16 + l16;
        float bb = bias[colg];
#pragma unroll
        for (int mt = 0; mt < 4; mt++)
#pragma unroll
            for (int r = 0; r < 4; r++)
                tl[(mt * 16 + quad * 4 + r) * TLS + colg] = f2bf(acc[mt][nt][r] + bb);
    }
    __syncthreads();

    // ---- phase 4a: coalesced global store ----
    for (int i = tid; i < 64 * 64; i += 512) {
        int r = i >> 6, c4 = i & 63;
        int v = m0 + r;
        if (v < N_NODES)
            ((ushort4*)hout)[(size_t)v * 64 + c4] = *(ushort4*)(tl + r * TLS + c4 * 4);
    }
    // ---- phase 4b: fused readout; half 0 -> rows 0..31, half 1 -> 32..63 ----
    {
        int c = tid & 255;
        int r0 = (tid >> 8) * 32;
        float a2 = 0.f;
        int curg = gl[r0];
        for (int r = r0; r < r0 + 32; r++) {
            int g = gl[r];
            if (g < 0) break;
            if (g != curg) {
                atomicAdd(&GsumL[curg * HIDDEN + c], a2);
                a2 = 0.f;
                curg = g;
            }
            a2 += bf2f(tl[r * TLS + c]);
        }
        if (curg >= 0) atomicAdd(&GsumL[curg * HIDDEN + c], a2);
    }
}

// ================= out[g] = (concat gmean) @ W_out + b_out ==================
__global__ __launch_bounds__(256) void k_out(const float* __restrict__ Gsum,
                                             const int* __restrict__ gcnt,
                                             const float* __restrict__ Wout,
                                             const float* __restrict__ bout,
                                             float* __restrict__ out) {
    int g = blockIdx.x;
    int c = threadIdx.x;
    __shared__ float gm[HIDDEN * CONV_NUMS];
    float invc = 1.0f / fmaxf((float)gcnt[g], 1.0f);
    for (int i = c; i < HIDDEN * CONV_NUMS; i += 256) {
        int l = i >> 8;
        int k = i & 255;
        gm[i] = Gsum[(size_t)l * N_GRAPHS * HIDDEN + g * HIDDEN + k] * invc;
    }
    __syncthreads();
    float acc = bout[c];
    const float4* gm4 = (const float4*)gm;
    for (int k0 = 0; k0 < HIDDEN * CONV_NUMS; k0 += 4) {
        float4 gv = gm4[k0 >> 2];
        acc += gv.x * Wout[(k0 + 0) * HIDDEN + c];
        acc += gv.y * Wout[(k0 + 1) * HIDDEN + c];
        acc += gv.z * Wout[(k0 + 2) * HIDDEN + c];
        acc += gv.w * Wout[(k0 + 3) * HIDDEN + c];
    }
    out[g * HIDDEN + c] = acc;
}

extern "C" void kernel_launch(void* const* d_in, const int* in_sizes, int n_in,
                              void* d_out, int out_size, void* d_ws, size_t ws_size,
                              hipStream_t stream) {
    const float* X    = (const float*)d_in[0];
    const int*   src  = (const int*)d_in[1];
    const int*   dst  = (const int*)d_in[2];
    const int*   gid  = (const int*)d_in[3];
    const float* Wp   = (const float*)d_in[4];
    const float* bp   = (const float*)d_in[5];
    const float* Wl   = (const float*)d_in[6];
    const float* bl   = (const float*)d_in[7];
    const float* Wout = (const float*)d_in[8];
    const float* bout = (const float*)d_in[9];
    float* out = (float*)d_out;

    char* ws = (char*)d_ws;
    size_t off = 0;
    auto alloc = [&](size_t bytes) {
        char* p = ws + off;
        off += (bytes + 255) & ~size_t(255);
        return p;
    };
    unsigned short* h     = (unsigned short*)alloc(sizeof(short) * N_NODES * HIDDEN);
    unsigned short* t     = (unsigned short*)alloc(sizeof(short) * N_NODES * HIDDEN);
    unsigned short* Wpack = (unsigned short*)alloc(sizeof(short) * HIDDEN * HIDDEN);
    int2*  pairs   = (int2*)alloc(sizeof(int2) * N_EDGES);
    int*   col     = (int*)alloc(sizeof(int) * N_EDGES);
    int*   row_ptr = (int*)alloc(sizeof(int) * (N_NODES + 1));
    int*   bucket_base   = (int*)alloc(sizeof(int) * (NBK + 1));
    int*   bucket_cursor = (int*)alloc(sizeof(int) * NBK);
    int*   bucket_cnt    = (int*)alloc(sizeof(int) * NBK);
    float* Gsum    = (float*)alloc(sizeof(float) * CONV_NUMS * N_GRAPHS * HIDDEN);
    int*   gcnt    = (int*)alloc(sizeof(int) * N_GRAPHS);

    hipMemsetAsync(bucket_cnt, 0, sizeof(int) * NBK, stream);
    hipMemsetAsync(Gsum, 0, sizeof(float) * CONV_NUMS * N_GRAPHS * HIDDEN, stream);
    hipMemsetAsync(gcnt, 0, sizeof(int) * N_GRAPHS, stream);

    k_passA<<<512, 256, 0, stream>>>(dst, gid, bucket_cnt, gcnt);
    k_bscan<<<1, 256, 0, stream>>>(bucket_cnt, bucket_base, bucket_cursor, row_ptr);
    k_passB<<<(N_EDGES + BCH - 1) / BCH, 256, 0, stream>>>(src, dst, bucket_cursor, pairs);
    k_passC<<<NBK, 256, 0, stream>>>(pairs, bucket_base, row_ptr, col);
    k_pack_w<<<32, 256, 0, stream>>>(Wl, Wpack);

    k_proj<<<(N_NODES + 255) / 256, 256, 0, stream>>>(X, Wp, bp, h);

    unsigned short* cur = h;
    unsigned short* nxt = t;
    for (int l = 0; l < CONV_NUMS; l++) {
        k_layer<<<(N_NODES + 63) / 64, 512, 0, stream>>>(
            cur, row_ptr, col, Wpack, bl, gid, nxt,
            Gsum + (size_t)l * N_GRAPHS * HIDDEN);
        unsigned short* tmp = cur; cur = nxt; nxt = tmp;
    }

    k_out<<<N_GRAPHS, 256, 0, stream>>>(Gsum, gcnt, Wout, bout, out);
}